// Round 5
// baseline (1149.421 us; speedup 1.0000x reference)
//
#include <hip/hip_runtime.h>
#include <hip/hip_fp16.h>
#include <math.h>

// Problem constants: H=4 heads, C=32, HID=128, 3 layers, B=2048, D=480
#define NHEAD   4
#define CDIM    32
#define HIDDIM  128
#define NLAYERS 3
#define DIN     480
#define LN_EPS  1e-5f
#define NSPLIT  4    // dst-range owners for locality-split CSR fill

typedef _Float16 f16x8 __attribute__((ext_vector_type(8)));
typedef float    f32x4 __attribute__((ext_vector_type(4)));
typedef int      int4u __attribute__((ext_vector_type(4), aligned(4)));  // 4B-aligned int4 load

// ---------------------------------------------------------------------------
// Combined-graph CSR build. Node ids: tcr [0,Nt), pep [Nt,Nt+Np).
// ---------------------------------------------------------------------------
__global__ void hist_kernel(const int* __restrict__ tei, const int* __restrict__ pei,
                            int* __restrict__ deg, int Et, int Ep, int Nt, int N) {
    int i = blockIdx.x * 256 + threadIdx.x;
    int tot = Et + Ep + N;
    if (i >= tot) return;
    int d;
    if (i < Et)            d = tei[Et + i];
    else if (i < Et + Ep)  d = pei[Ep + (i - Et)] + Nt;
    else                   d = i - Et - Ep;
    atomicAdd(&deg[d], 1);
}

// Owner-split fill: blocks with blockIdx%NSPLIT==o only write edges whose dst
// falls in owner-range o (dst*NSPLIT/N). Confines each col region to ~2 XCDs'
// L2s over a short window so scattered 4B writes combine into full lines
// (WRITE_SIZE was 150MB for a 9.8MB payload before; ~6x less after).
__global__ __launch_bounds__(256) void fill_kernel(const int* __restrict__ tei,
                                                   const int* __restrict__ pei,
                                                   int* __restrict__ cursor,
                                                   int* __restrict__ col,
                                                   int Et, int Ep, int Nt, int N,
                                                   float oscale) {
    int oid    = blockIdx.x & (NSPLIT - 1);
    int chunk  = blockIdx.x / NSPLIT;
    int nchunk = gridDim.x / NSPLIT;
    int tot = Et + Ep + N;
    int per = (tot + nchunk - 1) / nchunk;
    int e0 = chunk * per;
    int e1 = min(e0 + per, tot);
    for (int i = e0 + (int)threadIdx.x; i < e1; i += 256) {
        int d;
        bool self = false;
        if (i < Et)           d = tei[Et + i];
        else if (i < Et + Ep) d = pei[Ep + (i - Et)] + Nt;
        else                { d = i - Et - Ep; self = true; }
        int owner = (int)((float)d * oscale);
        owner = owner > NSPLIT - 1 ? NSPLIT - 1 : owner;
        if (owner != oid) continue;
        int s;
        if (self)        s = d;
        else if (i < Et) s = tei[i];
        else             s = pei[i - Et] + Nt;
        int pos = atomicAdd(&cursor[d], 1);
        col[pos] = s;
    }
}

// ---------------------------------------------------------------------------
// Hierarchical exclusive scan: 1024 elems/block, int4 coalesced.
// ---------------------------------------------------------------------------
__global__ __launch_bounds__(256) void scan_reduce(const int* __restrict__ deg,
                                                   int* __restrict__ part, int N) {
    __shared__ int sm[256];
    int t = threadIdx.x;
    int base = blockIdx.x * 1024 + t * 4;
    int4 v = make_int4(0, 0, 0, 0);
    if (base + 3 < N) v = *(const int4*)(deg + base);
    else if (base < N) {
        v.x = deg[base];
        if (base + 1 < N) v.y = deg[base + 1];
        if (base + 2 < N) v.z = deg[base + 2];
    }
    sm[t] = v.x + v.y + v.z + v.w;
    __syncthreads();
    for (int off = 128; off >= 1; off >>= 1) {
        if (t < off) sm[t] += sm[t + off];
        __syncthreads();
    }
    if (t == 0) part[blockIdx.x] = sm[0];
}

__global__ __launch_bounds__(256) void scan_partials(int* __restrict__ part,
                                                     int* __restrict__ rowptr,
                                                     int npart, int N) {
    __shared__ int sm[256];
    int t = threadIdx.x;
    sm[t] = (t < npart) ? part[t] : 0;
    __syncthreads();
    for (int off = 1; off < 256; off <<= 1) {
        int u = (t >= off) ? sm[t - off] : 0;
        __syncthreads();
        sm[t] += u;
        __syncthreads();
    }
    if (t < npart) part[t] = (t == 0) ? 0 : sm[t - 1];
    if (t == 0) rowptr[N] = sm[255];
}

__global__ __launch_bounds__(256) void scan_final(const int* __restrict__ deg,
                                                  const int* __restrict__ part,
                                                  int* __restrict__ rowptr,
                                                  int* __restrict__ cursor, int N) {
    __shared__ int sm[256];
    int t = threadIdx.x;
    int base = blockIdx.x * 1024 + t * 4;
    int4 v = make_int4(0, 0, 0, 0);
    if (base + 3 < N) v = *(const int4*)(deg + base);
    else if (base < N) {
        v.x = deg[base];
        if (base + 1 < N) v.y = deg[base + 1];
        if (base + 2 < N) v.z = deg[base + 2];
    }
    sm[t] = v.x + v.y + v.z + v.w;
    __syncthreads();
    for (int off = 1; off < 256; off <<= 1) {
        int u = (t >= off) ? sm[t - off] : 0;
        __syncthreads();
        sm[t] += u;
        __syncthreads();
    }
    int run = ((t == 0) ? 0 : sm[t - 1]) + part[blockIdx.x];
    if (base < N)     { rowptr[base]     = run; cursor[base]     = run; run += v.x; }
    if (base + 1 < N) { rowptr[base + 1] = run; cursor[base + 1] = run; run += v.y; }
    if (base + 2 < N) { rowptr[base + 2] = run; cursor[base + 2] = run; run += v.z; }
    if (base + 3 < N) { rowptr[base + 3] = run; cursor[base + 3] = run; }
}

// ---------------------------------------------------------------------------
// Weight prep, single launch: W_in [480][128] -> WtIn [128][480] f16 and
// Wg [3][128][128] -> WtG [3][128][128] f16 (transposed, cast).
// ---------------------------------------------------------------------------
__global__ __launch_bounds__(256) void transpose_all(const float* __restrict__ W_in,
                                                     const float* __restrict__ Wg,
                                                     _Float16* __restrict__ WtIn,
                                                     _Float16* __restrict__ WtG) {
    int idx = blockIdx.x * 256 + threadIdx.x;
    const int NIN = 128 * DIN;
    if (idx < NIN) {
        int n = idx / DIN, k = idx - n * DIN;
        WtIn[idx] = (_Float16)W_in[(size_t)k * 128 + n];
    } else {
        int r = idx - NIN;
        if (r >= NLAYERS * 128 * 128) return;
        int l = r / (128 * 128), rr = r - l * 128 * 128;
        int n = rr >> 7, k = rr & 127;
        WtG[(size_t)l * 128 * 128 + rr] =
            (_Float16)Wg[(size_t)l * 128 * 128 + (size_t)k * 128 + n];
    }
}

// ---------------------------------------------------------------------------
// MFMA fp16 GEMM: C[n,j] = act(A[n,:] @ W[:,j] (+bias)), 128 output cols.
// Block 256 (4 waves); tile 64 rows x 128 cols; K-step 32.
// Wt is pre-transposed [128][K] f16. A is f32, cast to f16 during staging.
// A2/NtRows: optional second input matrix (combined-row proj GEMM) — blocks
// with bn >= NtRows read A2 at row bn-NtRows. C always indexed by combined bn.
// Fragment layouts (gfx950 16x16x32): A/B lane: [m|n=lane&15][k=quad*8+j];
// C/D lane: col=lane&15, row=quad*4+reg.
// OUT_F16=1: f16 out, no bias/act, PLUS fused attention scores: per-head dot
// of the f32 accumulator row with a_src/a_dst, 16-lane xor-reduce, one
// (row,head) write per lane.
// ---------------------------------------------------------------------------
#define ASTRIDE 40   // halves; 80 B row stride: 16B-aligned, 2-way banks (free)

template<int OUT_F16>
__global__ __launch_bounds__(256) void mfma_gemm(const float* __restrict__ A,
                                                 const float* __restrict__ A2,
                                                 int NtRows,
                                                 const _Float16* __restrict__ Wt,
                                                 const float* __restrict__ bias,
                                                 void* __restrict__ Cout,
                                                 const float* __restrict__ a_src,
                                                 const float* __restrict__ a_dst,
                                                 float* __restrict__ ssrc,
                                                 float* __restrict__ sdst,
                                                 int K) {
    __shared__ _Float16 As[64 * ASTRIDE];
    __shared__ _Float16 Ws[128 * ASTRIDE];
    const int tid  = threadIdx.x;
    const int bn   = blockIdx.x * 64;
    const int wave = tid >> 6, lane = tid & 63;
    const int lm   = lane & 15, q = lane >> 4;

    const float* __restrict__ Abase;
    int arow;
    if (A2 && bn >= NtRows) { Abase = A2; arow = bn - NtRows; }
    else                    { Abase = A;  arow = bn; }

    f32x4 acc[8];
#pragma unroll
    for (int i = 0; i < 8; ++i) acc[i] = (f32x4){0.f, 0.f, 0.f, 0.f};

    for (int kt = 0; kt < K; kt += 32) {
        // Stage A tile: 64 rows x 32 cols, f32 -> f16 (coalesced float4 loads)
#pragma unroll
        for (int p = 0; p < 2; ++p) {
            int f  = p * 256 + tid;          // float4 index in [0,512)
            int r  = f >> 3;
            int c4 = (f & 7) * 4;
            float4 v = *(const float4*)(Abase + (size_t)(arow + r) * K + kt + c4);
            _Float16* d = &As[r * ASTRIDE + c4];
            d[0] = (_Float16)v.x; d[1] = (_Float16)v.y;
            d[2] = (_Float16)v.z; d[3] = (_Float16)v.w;
        }
        // Stage Wt tile: 128 rows(n) x 32 k halves (straight copy, coalesced)
#pragma unroll
        for (int p = 0; p < 2; ++p) {
            int f   = p * 256 + tid;         // 8-half segment index in [0,512)
            int n   = f >> 2;
            int seg = (f & 3) * 8;
            *(float4*)(&Ws[n * ASTRIDE + seg]) =
                *(const float4*)(Wt + (size_t)n * K + kt + seg);
        }
        __syncthreads();
        f16x8 af = *(const f16x8*)(&As[(wave * 16 + lm) * ASTRIDE + q * 8]);
#pragma unroll
        for (int nt = 0; nt < 8; ++nt) {
            f16x8 bf = *(const f16x8*)(&Ws[(nt * 16 + lm) * ASTRIDE + q * 8]);
            acc[nt] = __builtin_amdgcn_mfma_f32_16x16x32_f16(af, bf, acc[nt], 0, 0, 0);
        }
        __syncthreads();
    }

    const int row0 = bn + wave * 16 + q * 4;
    if (OUT_F16) {
        _Float16* C = (_Float16*)Cout;
        float as[8], ad[8];
#pragma unroll
        for (int nt = 0; nt < 8; ++nt) {
            as[nt] = a_src[nt * 16 + lm];
            ad[nt] = a_dst[nt * 16 + lm];
        }
        float myS = 0.f, myD = 0.f;
#pragma unroll
        for (int i = 0; i < 4; ++i) {
            float ps[4], pd[4];
#pragma unroll
            for (int h = 0; h < 4; ++h) {
                ps[h] = as[2 * h] * acc[2 * h][i] + as[2 * h + 1] * acc[2 * h + 1][i];
                pd[h] = ad[2 * h] * acc[2 * h][i] + ad[2 * h + 1] * acc[2 * h + 1][i];
            }
#pragma unroll
            for (int k = 1; k < 16; k <<= 1) {
#pragma unroll
                for (int h = 0; h < 4; ++h) {
                    ps[h] += __shfl_xor(ps[h], k, 16);
                    pd[h] += __shfl_xor(pd[h], k, 16);
                }
            }
            if ((lm >> 2) == i) { myS = ps[lm & 3]; myD = pd[lm & 3]; }
#pragma unroll
            for (int nt = 0; nt < 8; ++nt)
                C[(size_t)(row0 + i) * 128 + nt * 16 + lm] = (_Float16)acc[nt][i];
        }
        int sr = (row0 + (lm >> 2)) * 4 + (lm & 3);
        ssrc[sr] = myS;
        sdst[sr] = myD;
    } else {
        float* C = (float*)Cout;
#pragma unroll
        for (int nt = 0; nt < 8; ++nt) {
            int c = nt * 16 + lm;
            float bv = bias[c];
#pragma unroll
            for (int i = 0; i < 4; ++i)
                C[(size_t)(row0 + i) * 128 + c] = fmaxf(acc[nt][i] + bv, 0.f);
        }
    }
}

// ---------------------------------------------------------------------------
// Fused gather with ONLINE softmax — 4 nodes per wave, 16 lanes per node,
// 8 channels per lane. SOFTWARE-PIPELINED: the next 4-edge chunk's col vector,
// value rows and ssrc scores are prefetched before the current chunk's
// exp/FMA block, moving load-issue ~120 cycles ahead of use (covers L2/L3
// latency; the FMA block previously stalled on vmcnt right after issue).
// Math order identical to the non-pipelined version (absmax-safe).
// Then /z + bias + LayerNorm (16-lane reduce) + ReLU + residual.
// ---------------------------------------------------------------------------
__global__ __launch_bounds__(256) void gather_kernel(const f16x8* __restrict__ h2v,
                                                     const float* __restrict__ ssrc,
                                                     const float* __restrict__ sdst,
                                                     const int* __restrict__ rowptr,
                                                     const int* __restrict__ col,
                                                     const float* __restrict__ bg,
                                                     const float* __restrict__ gamma,
                                                     const float* __restrict__ beta,
                                                     float* __restrict__ hio, int N) {
    int wave = threadIdx.x >> 6, lane = threadIdx.x & 63;
    int g = lane >> 4, t = lane & 15;       // group g handles node n; lane t -> ch [8t,8t+8)
    int n = blockIdx.x * 16 + wave * 4 + g;
    bool valid = n < N;
    int nn = valid ? n : 0;
    int head = t >> 2;
    int beg = rowptr[nn];
    int end = valid ? rowptr[nn + 1] : beg;
    float sd = sdst[nn * 4 + head];

    float m = -1e30f, z = 0.f;
    float a[8];
#pragma unroll
    for (int k = 0; k < 8; ++k) a[k] = 0.f;

    auto compute4 = [&](f16x8 v0, f16x8 v1, f16x8 v2, f16x8 v3,
                        float x0, float x1, float x2, float x3) {
        float e0 = x0 + sd; e0 = fmaxf(e0, 0.2f * e0);   // leaky_relu
        float e1 = x1 + sd; e1 = fmaxf(e1, 0.2f * e1);
        float e2 = x2 + sd; e2 = fmaxf(e2, 0.2f * e2);
        float e3 = x3 + sd; e3 = fmaxf(e3, 0.2f * e3);
        float nm = fmaxf(fmaxf(fmaxf(e0, e1), fmaxf(e2, e3)), m);
        float r  = __expf(m - nm);          // 0 on first chunk, 1 if no new max
        m = nm;
        float p0 = __expf(e0 - nm);
        float p1 = __expf(e1 - nm);
        float p2 = __expf(e2 - nm);
        float p3 = __expf(e3 - nm);
        z = z * r + (p0 + p1 + p2 + p3);
#pragma unroll
        for (int k = 0; k < 8; ++k) a[k] *= r;
#pragma unroll
        for (int k = 0; k < 8; ++k) a[k] = fmaf((float)v0[k], p0, a[k]);
#pragma unroll
        for (int k = 0; k < 8; ++k) a[k] = fmaf((float)v1[k], p1, a[k]);
#pragma unroll
        for (int k = 0; k < 8; ++k) a[k] = fmaf((float)v2[k], p2, a[k]);
#pragma unroll
        for (int k = 0; k < 8; ++k) a[k] = fmaf((float)v3[k], p3, a[k]);
    };

    int j = beg;
    int nch = (end - beg) >> 2;
    if (nch > 0) {
        int4u cv = *(const int4u*)(col + j);
        f16x8 v0 = h2v[(size_t)cv.x * 16 + t];
        f16x8 v1 = h2v[(size_t)cv.y * 16 + t];
        f16x8 v2 = h2v[(size_t)cv.z * 16 + t];
        f16x8 v3 = h2v[(size_t)cv.w * 16 + t];
        float x0 = ssrc[cv.x * 4 + head];
        float x1 = ssrc[cv.y * 4 + head];
        float x2 = ssrc[cv.z * 4 + head];
        float x3 = ssrc[cv.w * 4 + head];
        for (int c = 1; c < nch; ++c) {
            j += 4;
            int4u cn = *(const int4u*)(col + j);
            f16x8 w0 = h2v[(size_t)cn.x * 16 + t];
            f16x8 w1 = h2v[(size_t)cn.y * 16 + t];
            f16x8 w2 = h2v[(size_t)cn.z * 16 + t];
            f16x8 w3 = h2v[(size_t)cn.w * 16 + t];
            float u0 = ssrc[cn.x * 4 + head];
            float u1 = ssrc[cn.y * 4 + head];
            float u2 = ssrc[cn.z * 4 + head];
            float u3 = ssrc[cn.w * 4 + head];
            compute4(v0, v1, v2, v3, x0, x1, x2, x3);
            v0 = w0; v1 = w1; v2 = w2; v3 = w3;
            x0 = u0; x1 = u1; x2 = u2; x3 = u3;
        }
        compute4(v0, v1, v2, v3, x0, x1, x2, x3);
        j += 4;
    }
    for (; j < end; ++j) {
        int s = col[j];
        float e = ssrc[s * 4 + head] + sd;
        e = fmaxf(e, 0.2f * e);
        f16x8 v = h2v[(size_t)s * 16 + t];
        float nm = fmaxf(m, e);
        float r  = __expf(m - nm);
        float p  = __expf(e - nm);
        m = nm;
        z = z * r + p;
#pragma unroll
        for (int k = 0; k < 8; ++k) a[k] = fmaf((float)v[k], p, a[k] * r);
    }

    if (!valid) return;
    float inv = 1.f / z;
    int c0 = t * 8;
    float4 bgv0 = *(const float4*)(bg + c0);
    float4 bgv1 = *(const float4*)(bg + c0 + 4);
    float o[8];
    o[0] = a[0] * inv + bgv0.x; o[1] = a[1] * inv + bgv0.y;
    o[2] = a[2] * inv + bgv0.z; o[3] = a[3] * inv + bgv0.w;
    o[4] = a[4] * inv + bgv1.x; o[5] = a[5] * inv + bgv1.y;
    o[6] = a[6] * inv + bgv1.z; o[7] = a[7] * inv + bgv1.w;
    float s = 0.f;
#pragma unroll
    for (int k = 0; k < 8; ++k) s += o[k];
#pragma unroll
    for (int k = 1; k < 16; k <<= 1) s += __shfl_xor(s, k, 16);
    float mu = s * (1.f / 128.f);
    float q = 0.f;
#pragma unroll
    for (int k = 0; k < 8; ++k) q += (o[k] - mu) * (o[k] - mu);
#pragma unroll
    for (int k = 1; k < 16; k <<= 1) q += __shfl_xor(q, k, 16);
    float rs = rsqrtf(q * (1.f / 128.f) + LN_EPS);
    float4 gm0 = *(const float4*)(gamma + c0);
    float4 gm1 = *(const float4*)(gamma + c0 + 4);
    float4 bt0 = *(const float4*)(beta + c0);
    float4 bt1 = *(const float4*)(beta + c0 + 4);
    float* hrow = hio + (size_t)n * 128 + c0;
    float4 r0 = *(const float4*)(hrow);
    float4 r1 = *(const float4*)(hrow + 4);
    float4 y0, y1;
    y0.x = fmaxf((o[0] - mu) * rs * gm0.x + bt0.x, 0.f) + r0.x;
    y0.y = fmaxf((o[1] - mu) * rs * gm0.y + bt0.y, 0.f) + r0.y;
    y0.z = fmaxf((o[2] - mu) * rs * gm0.z + bt0.z, 0.f) + r0.z;
    y0.w = fmaxf((o[3] - mu) * rs * gm0.w + bt0.w, 0.f) + r0.w;
    y1.x = fmaxf((o[4] - mu) * rs * gm1.x + bt1.x, 0.f) + r1.x;
    y1.y = fmaxf((o[5] - mu) * rs * gm1.y + bt1.y, 0.f) + r1.y;
    y1.z = fmaxf((o[6] - mu) * rs * gm1.z + bt1.z, 0.f) + r1.z;
    y1.w = fmaxf((o[7] - mu) * rs * gm1.w + bt1.w, 0.f) + r1.w;
    *(float4*)(hrow)     = y0;
    *(float4*)(hrow + 4) = y1;
}

// ---------------------------------------------------------------------------
// Fused global-mean-pool + classifier MLP. batch arrays are SORTED, so each
// batch element owns contiguous node ranges (binary-searched, broadcast
// loads). Block r: sum+normalize tcr range -> z[0:128], pep range ->
// z[128:256], then [256]->relu128->relu64->sigmoid. No pooled buffer.
// ---------------------------------------------------------------------------
__global__ __launch_bounds__(128) void pool_classifier_kernel(
        const float* __restrict__ h,
        const int* __restrict__ tb, const int* __restrict__ pb,
        const float* __restrict__ Wc1, const float* __restrict__ bc1,
        const float* __restrict__ Wc2, const float* __restrict__ bc2,
        const float* __restrict__ Wc3, const float* __restrict__ bc3,
        float* __restrict__ outp, int Nt, int Np, int B) {
    __shared__ float z[256];
    __shared__ float a1[128];
    __shared__ float a2[64];
    int r = blockIdx.x, t = threadIdx.x;
    // --- tcr pool ---
    {
        int lo = 0, hi = Nt;
        while (lo < hi) { int mid = (lo + hi) >> 1; if (tb[mid] < r) lo = mid + 1; else hi = mid; }
        int beg = lo;
        hi = Nt;
        while (lo < hi) { int mid = (lo + hi) >> 1; if (tb[mid] < r + 1) lo = mid + 1; else hi = mid; }
        int end = lo;
        float s0 = 0.f, s1 = 0.f, s2 = 0.f, s3 = 0.f;
        int n = beg;
        for (; n + 3 < end; n += 4) {
            s0 += h[(size_t)n * 128 + t];
            s1 += h[(size_t)(n + 1) * 128 + t];
            s2 += h[(size_t)(n + 2) * 128 + t];
            s3 += h[(size_t)(n + 3) * 128 + t];
        }
        for (; n < end; ++n) s0 += h[(size_t)n * 128 + t];
        float invc = 1.f / (float)max(end - beg, 1);
        z[t] = ((s0 + s1) + (s2 + s3)) * invc;
    }
    // --- pep pool ---
    {
        int lo = 0, hi = Np;
        while (lo < hi) { int mid = (lo + hi) >> 1; if (pb[mid] < r) lo = mid + 1; else hi = mid; }
        int beg = lo;
        hi = Np;
        while (lo < hi) { int mid = (lo + hi) >> 1; if (pb[mid] < r + 1) lo = mid + 1; else hi = mid; }
        int end = lo;
        float s0 = 0.f, s1 = 0.f, s2 = 0.f, s3 = 0.f;
        int n = beg;
        for (; n + 3 < end; n += 4) {
            s0 += h[(size_t)(Nt + n) * 128 + t];
            s1 += h[(size_t)(Nt + n + 1) * 128 + t];
            s2 += h[(size_t)(Nt + n + 2) * 128 + t];
            s3 += h[(size_t)(Nt + n + 3) * 128 + t];
        }
        for (; n < end; ++n) s0 += h[(size_t)(Nt + n) * 128 + t];
        float invc = 1.f / (float)max(end - beg, 1);
        z[128 + t] = ((s0 + s1) + (s2 + s3)) * invc;
    }
    __syncthreads();
    float acc = bc1[t];
    for (int k = 0; k < 256; ++k) acc = fmaf(z[k], Wc1[k * 128 + t], acc);
    a1[t] = fmaxf(acc, 0.f);
    __syncthreads();
    if (t < 64) {
        float a = bc2[t];
        for (int k = 0; k < 128; ++k) a = fmaf(a1[k], Wc2[k * 64 + t], a);
        a2[t] = fmaxf(a, 0.f);
    }
    __syncthreads();
    if (t < 64) {
        float p = a2[t] * Wc3[t];
#pragma unroll
        for (int k = 1; k < 64; k <<= 1) p += __shfl_xor(p, k);
        if (t == 0) outp[r] = 1.f / (1.f + __expf(-(p + bc3[0])));
    }
}

// ---------------------------------------------------------------------------
// Host orchestration — combined graph, fp16 MFMA GEMMs with fused scores,
// pipelined online-softmax gather, fused pool+classifier. 15 launches.
// ---------------------------------------------------------------------------
extern "C" void kernel_launch(void* const* d_in, const int* in_sizes, int n_in,
                              void* d_out, int out_size, void* d_ws, size_t ws_size,
                              hipStream_t stream) {
    const float* tcr_x     = (const float*)d_in[0];
    const int*   tcr_ei    = (const int*)d_in[1];
    const int*   tcr_batch = (const int*)d_in[2];
    const float* pep_x     = (const float*)d_in[3];
    const int*   pep_ei    = (const int*)d_in[4];
    const int*   pep_batch = (const int*)d_in[5];
    const float* W_in      = (const float*)d_in[6];
    const float* b_in      = (const float*)d_in[7];
    const float* Wg        = (const float*)d_in[8];
    const float* bg        = (const float*)d_in[9];
    const float* att_src   = (const float*)d_in[10];
    const float* att_dst   = (const float*)d_in[11];
    const float* ln_gamma  = (const float*)d_in[12];
    const float* ln_beta   = (const float*)d_in[13];
    const float* Wc1       = (const float*)d_in[14];
    const float* bc1       = (const float*)d_in[15];
    const float* Wc2       = (const float*)d_in[16];
    const float* bc2       = (const float*)d_in[17];
    const float* Wc3       = (const float*)d_in[18];
    const float* bc3       = (const float*)d_in[19];

    const int Nt = in_sizes[0] / DIN;
    const int Et = in_sizes[1] / 2;
    const int Np = in_sizes[3] / DIN;
    const int Ep = in_sizes[4] / 2;
    const int B  = out_size;
    const int N  = Nt + Np;
    const int Etot = Et + Ep + N;

    char* w = (char*)d_ws;
    size_t o = 0;
    auto alloc = [&](size_t bytes) -> char* {
        size_t r = (o + 255) & ~(size_t)255;
        o = r + bytes;
        return w + r;
    };
    float*    h_a    = (float*)alloc((size_t)N * 128 * 4);   // residual stream (f32)
    _Float16* h2h    = (_Float16*)alloc((size_t)N * 128 * 2); // projected feats (f16)
    _Float16* WtIn   = (_Float16*)alloc((size_t)128 * DIN * 2);
    _Float16* WtG    = (_Float16*)alloc((size_t)NLAYERS * 128 * 128 * 2);
    float*    ssrc   = (float*)alloc((size_t)N * 4 * 4);
    float*    sdst   = (float*)alloc((size_t)N * 4 * 4);
    int* rowptr      = (int*)alloc((size_t)(N + 1) * 4);
    int* cursor      = (int*)alloc((size_t)N * 4);
    int* deg         = (int*)alloc((size_t)N * 4);
    int* part        = (int*)alloc(256 * 4);
    int* col         = (int*)alloc((size_t)Etot * 4);
    (void)ws_size; (void)n_in;

    hipMemsetAsync(deg, 0, (size_t)N * 4, stream);

    // Weight prep (transpose + f16 cast), single launch
    transpose_all<<<(128 * DIN + NLAYERS * 128 * 128 + 255) / 256, 256, 0, stream>>>(
        W_in, Wg, WtIn, WtG);

    // CSR build (combined, built once, reused by all 3 layers)
    hist_kernel<<<(Etot + 255) / 256, 256, 0, stream>>>(tcr_ei, pep_ei, deg, Et, Ep, Nt, N);
    int nblk = (N + 1023) / 1024;
    scan_reduce<<<nblk, 256, 0, stream>>>(deg, part, N);
    scan_partials<<<1, 256, 0, stream>>>(part, rowptr, nblk, N);
    scan_final<<<nblk, 256, 0, stream>>>(deg, part, rowptr, cursor, N);
    // Owner-split fill: 4 owners x 512 chunks = 2048 blocks
    fill_kernel<<<NSPLIT * 512, 256, 0, stream>>>(tcr_ei, pep_ei, cursor, col,
                                                  Et, Ep, Nt, N, (float)NSPLIT / (float)N);

    // Input projection + relu -> combined residual stream (single merged launch)
    mfma_gemm<0><<<N / 64, 256, 0, stream>>>(tcr_x, pep_x, Nt, WtIn, b_in, h_a,
                                             nullptr, nullptr, nullptr, nullptr, DIN);

    for (int i = 0; i < NLAYERS; ++i) {
        mfma_gemm<1><<<N / 64, 256, 0, stream>>>(h_a, nullptr, 0x40000000,
                                                 WtG + (size_t)i * 128 * 128,
                                                 nullptr, h2h,
                                                 att_src + i * NHEAD * CDIM,
                                                 att_dst + i * NHEAD * CDIM,
                                                 ssrc, sdst, 128);
        gather_kernel<<<(N + 15) / 16, 256, 0, stream>>>((const f16x8*)h2h, ssrc, sdst,
                                                         rowptr, col, bg + i * HIDDIM,
                                                         ln_gamma + i * HIDDIM,
                                                         ln_beta + i * HIDDIM, h_a, N);
    }
    pool_classifier_kernel<<<B, 128, 0, stream>>>(h_a, tcr_batch, pep_batch,
                                                  Wc1, bc1, Wc2, bc2, Wc3, bc3,
                                                  (float*)d_out, Nt, Np, B);
}